// Round 1
// baseline (345.305 us; speedup 1.0000x reference)
//
#include <hip/hip_runtime.h>

#define N_NODES 50000
#define N_EDGES 250000
#define N_GRAPHS 512
#define F_IN 32
#define F_EDGE 16
#define LATENT 32
#define EMBED 128
#define NT 8  // nodes per tile in fused kernel

// ---------------- CSR build (group edges by src) ----------------

__global__ void hist_kernel(const int* __restrict__ ei, int* __restrict__ deg) {
    int e = blockIdx.x * blockDim.x + threadIdx.x;
    if (e < N_EDGES) atomicAdd(&deg[ei[e]], 1);
}

__global__ __launch_bounds__(1024) void scan_kernel(const int* __restrict__ deg,
                                                    int* __restrict__ off,
                                                    int* __restrict__ cursor) {
    __shared__ int lsum[1024];
    int t = threadIdx.x;
    const int chunk = (N_NODES + 1023) >> 10;  // 49
    int s = t * chunk;
    int epos = s + chunk; if (epos > N_NODES) epos = N_NODES;
    if (s > N_NODES) s = N_NODES;
    int sum = 0;
    for (int i = s; i < epos; ++i) sum += deg[i];
    lsum[t] = sum;
    __syncthreads();
    if (t == 0) {
        int run = 0;
        for (int i = 0; i < 1024; ++i) { int v = lsum[i]; lsum[i] = run; run += v; }
    }
    __syncthreads();
    int run = lsum[t];
    for (int i = s; i < epos; ++i) { off[i] = run; cursor[i] = run; run += deg[i]; }
    if (t == 1023) off[N_NODES] = run;  // == N_EDGES
}

__global__ void scatter_kernel(const int* __restrict__ ei, int* __restrict__ cursor,
                               int* __restrict__ csr) {
    int e = blockIdx.x * blockDim.x + threadIdx.x;
    if (e < N_EDGES) {
        int s = ei[e];
        int p = atomicAdd(&cursor[s], 1);
        csr[p] = e;
    }
}

// ---------------- fused per-tile Z + edge message kernel ----------------
// Z[v][k][l] = sum_f x[v,f] * W2[k, f*32+l]   (k,l in [0,32), f in [0,32))
// B[v][l]    = sum_f x[v,f] * b2[f*32+l]
// msg_e[l]   = sum_k h_e[k] * Z[src_e][k][l] + B[src_e][l]
// h_e[k]     = relu(b1[k] + sum_f ea[e,f] * W1[f,k])

__global__ __launch_bounds__(256) void fused_edge_kernel(
    const float* __restrict__ x, const int* __restrict__ ei,
    const float* __restrict__ ea, const float* __restrict__ W1,
    const float* __restrict__ b1, const float* __restrict__ W2,
    const float* __restrict__ b2, const int* __restrict__ off,
    const int* __restrict__ csr, float* __restrict__ agg)
{
    __shared__ __attribute__((aligned(16))) float xsT[F_IN * NT];     // [f][n]
    __shared__ __attribute__((aligned(16))) float W1s[F_EDGE * LATENT]; // [f][k]
    __shared__ __attribute__((aligned(16))) float b1s[LATENT];
    __shared__ __attribute__((aligned(16))) float Zs[NT * LATENT * LATENT]; // [n][k][l]
    __shared__ __attribute__((aligned(16))) float Bs[NT * LATENT];          // [n][l]

    int t = threadIdx.x;
    int v0 = blockIdx.x * NT;

    // stage x tile (transposed) and W1/b1
    {
        int n = t >> 5, f = t & 31;            // 256 threads cover 8 nodes x 32 feats
        xsT[f * NT + n] = x[(v0 + n) * F_IN + f];
        W1s[t] = W1[t];                        // first 256 of 512
        W1s[t + 256] = W1[t + 256];
        if (t < LATENT) b1s[t] = b1[t];
    }
    __syncthreads();

    // ---- Z phase: thread owns (k, l4) for all n; W2 read exactly once per block
    {
        int k = t >> 3;             // 0..31
        int l4 = (t & 7) << 2;      // 0,4,...,28
        float4 acc[NT];
        #pragma unroll
        for (int n = 0; n < NT; ++n) acc[n] = make_float4(0.f, 0.f, 0.f, 0.f);
        #pragma unroll 4
        for (int f = 0; f < F_IN; ++f) {
            const float4 wv = *(const float4*)(W2 + k * (F_IN * LATENT) + f * LATENT + l4);
            const float4* xp = (const float4*)(xsT + f * NT);
            float4 xa = xp[0], xb = xp[1];
            const float xr[NT] = {xa.x, xa.y, xa.z, xa.w, xb.x, xb.y, xb.z, xb.w};
            #pragma unroll
            for (int n = 0; n < NT; ++n) {
                acc[n].x += xr[n] * wv.x;
                acc[n].y += xr[n] * wv.y;
                acc[n].z += xr[n] * wv.z;
                acc[n].w += xr[n] * wv.w;
            }
        }
        #pragma unroll
        for (int n = 0; n < NT; ++n)
            *(float4*)(Zs + n * (LATENT * LATENT) + k * LATENT + l4) = acc[n];
    }
    // ---- B row (bias b2 contribution): threads 0..63
    if (t < NT * 8) {
        int n = t >> 3; int l4 = (t & 7) << 2;
        float4 b = make_float4(0.f, 0.f, 0.f, 0.f);
        for (int f = 0; f < F_IN; ++f) {
            float xf = xsT[f * NT + n];
            const float4 bb = *(const float4*)(b2 + f * LATENT + l4);
            b.x += xf * bb.x; b.y += xf * bb.y; b.z += xf * bb.z; b.w += xf * bb.w;
        }
        *(float4*)(Bs + n * LATENT + l4) = b;
    }
    __syncthreads();

    // ---- edge phase: wave processes 2 edges per iteration (one per 32-lane half)
    int estart = off[v0];
    int eend = off[v0 + NT];
    int wave = t >> 6, lane = t & 63;
    int half = lane >> 5;
    int l = lane & 31;
    for (int p0 = estart + wave * 2; p0 < eend; p0 += 8) {
        int p = p0 + half;
        bool act = p < eend;
        if (act) {
            int e = csr[p];
            int s = ei[e];
            int n = s - v0;
            int d = ei[N_EDGES + e];
            const float* eap = ea + e * F_EDGE;
            // h[l] for this half's edge
            float h = b1s[l];
            #pragma unroll
            for (int f = 0; f < F_EDGE; ++f) h += eap[f] * W1s[f * LATENT + l];
            h = fmaxf(h, 0.0f);
            // msg[l] = B + sum_k h[k] * Z[n][k][l]
            float m = Bs[n * LATENT + l];
            const float* zp = Zs + n * (LATENT * LATENT) + l;
            #pragma unroll
            for (int kk = 0; kk < LATENT; ++kk) {
                float hk = __shfl(h, (lane & 32) | kk);
                m += hk * zp[kk * LATENT];
            }
            atomicAdd(&agg[d * LATENT + l], m);
        }
    }
}

// ---------------- node update + global mean pool (sums + counts) ----------------

__global__ void nodepool_kernel(const float* __restrict__ x, const float* __restrict__ agg,
                                const float* __restrict__ root, const float* __restrict__ cbias,
                                const int* __restrict__ batch, float* __restrict__ pool,
                                float* __restrict__ pcnt)
{
    int t = blockIdx.x * blockDim.x + threadIdx.x;
    int v = t >> 5, l = t & 31;
    if (v >= N_NODES) return;
    float a = agg[v * LATENT + l] + cbias[l];
    #pragma unroll 8
    for (int f = 0; f < F_IN; ++f) a += x[v * F_IN + f] * root[f * LATENT + l];
    a = fmaxf(a, 0.0f);
    int g = batch[v];
    atomicAdd(&pool[g * LATENT + l], a);
    if (l == 0) atomicAdd(&pcnt[g], 1.0f);
}

// ---------------- final FC ----------------

__global__ void final_kernel(const float* __restrict__ pool, const float* __restrict__ pcnt,
                             const float* __restrict__ fcw, const float* __restrict__ fcb,
                             float* __restrict__ out)
{
    int t = blockIdx.x * blockDim.x + threadIdx.x;
    int g = t >> 7, j = t & 127;
    if (g >= N_GRAPHS) return;
    float inv = 1.0f / fmaxf(pcnt[g], 1.0f);
    float o = fcb[j];
    #pragma unroll 8
    for (int l = 0; l < LATENT; ++l) {
        float pv = fmaxf(pool[g * LATENT + l] * inv, 0.0f);
        o += pv * fcw[l * EMBED + j];
    }
    out[g * EMBED + j] = o;
}

extern "C" void kernel_launch(void* const* d_in, const int* in_sizes, int n_in,
                              void* d_out, int out_size, void* d_ws, size_t ws_size,
                              hipStream_t stream)
{
    const float* x     = (const float*)d_in[0];
    const int*   ei    = (const int*)d_in[1];
    const float* ea    = (const float*)d_in[2];
    const int*   batch = (const int*)d_in[3];
    const float* W1    = (const float*)d_in[4];
    const float* b1    = (const float*)d_in[5];
    const float* W2    = (const float*)d_in[6];
    const float* b2    = (const float*)d_in[7];
    const float* root  = (const float*)d_in[8];
    const float* cb    = (const float*)d_in[9];
    const float* fcw   = (const float*)d_in[10];
    const float* fcb   = (const float*)d_in[11];
    float* out = (float*)d_out;

    char* w = (char*)d_ws;
    auto alloc = [&](size_t bytes) {
        char* p = w;
        w += (bytes + 255) & ~size_t(255);
        return p;
    };
    int*   deg    = (int*)alloc(N_NODES * 4);
    int*   off    = (int*)alloc((N_NODES + 1) * 4);
    int*   cursor = (int*)alloc(N_NODES * 4);
    int*   csr    = (int*)alloc(N_EDGES * 4);
    float* agg    = (float*)alloc((size_t)N_NODES * LATENT * 4);
    float* pool   = (float*)alloc(N_GRAPHS * LATENT * 4);
    float* pcnt   = (float*)alloc(N_GRAPHS * 4);

    hipMemsetAsync(deg, 0, N_NODES * 4, stream);
    hipMemsetAsync(agg, 0, (size_t)N_NODES * LATENT * 4, stream);
    hipMemsetAsync(pool, 0, N_GRAPHS * LATENT * 4, stream);
    hipMemsetAsync(pcnt, 0, N_GRAPHS * 4, stream);

    hist_kernel<<<(N_EDGES + 255) / 256, 256, 0, stream>>>(ei, deg);
    scan_kernel<<<1, 1024, 0, stream>>>(deg, off, cursor);
    scatter_kernel<<<(N_EDGES + 255) / 256, 256, 0, stream>>>(ei, cursor, csr);
    fused_edge_kernel<<<N_NODES / NT, 256, 0, stream>>>(x, ei, ea, W1, b1, W2, b2, off, csr, agg);
    nodepool_kernel<<<(N_NODES * LATENT + 255) / 256, 256, 0, stream>>>(x, agg, root, cb, batch, pool, pcnt);
    final_kernel<<<(N_GRAPHS * EMBED + 255) / 256, 256, 0, stream>>>(pool, pcnt, fcw, fcb, out);
}

// Round 2
// 232.339 us; speedup vs baseline: 1.4862x; 1.4862x over previous
//
#include <hip/hip_runtime.h>
#include <hip/hip_bf16.h>

#define N_NODES 50000
#define N_EDGES 250000
#define N_GRAPHS 512
#define F_IN 32
#define F_EDGE 16
#define LATENT 32
#define EMBED 128
#define NT 8                      // nodes per tile in fused kernel
#define N_TILES (N_NODES / NT)    // 6250

typedef unsigned short ushort;

__device__ inline ushort f2bf(float f) {
    __hip_bfloat16 b = __float2bfloat16(f);
    return *reinterpret_cast<ushort*>(&b);
}
__device__ inline float bf2f(ushort u) {
    __hip_bfloat16 b;
    *reinterpret_cast<ushort*>(&b) = u;
    return __bfloat162float(b);
}

// ---------------- zero workspace ----------------
__global__ void zero_kernel(int* __restrict__ deg, float4* __restrict__ agg4,
                            float* __restrict__ pool, float* __restrict__ pcnt) {
    int i = blockIdx.x * blockDim.x + threadIdx.x;
    if (i < (N_NODES * LATENT) / 4) agg4[i] = make_float4(0.f, 0.f, 0.f, 0.f);
    if (i < N_TILES) deg[i] = 0;
    if (i < N_GRAPHS * LATENT) pool[i] = 0.f;
    if (i < N_GRAPHS) pcnt[i] = 0.f;
}

// ---------------- tile-binned CSR build ----------------
__global__ void hist_kernel(const int* __restrict__ ei, int* __restrict__ deg) {
    int e = blockIdx.x * blockDim.x + threadIdx.x;
    if (e < N_EDGES) atomicAdd(&deg[ei[e] >> 3], 1);
}

__global__ __launch_bounds__(1024) void scan_kernel(const int* __restrict__ deg,
                                                    int* __restrict__ off,
                                                    int* __restrict__ cursor) {
    __shared__ int wsum[16];
    const int CH = 7;  // ceil(6250/1024)
    int t = threadIdx.x;
    int s = t * CH;
    int v[CH];
    int sum = 0;
    #pragma unroll
    for (int i = 0; i < CH; ++i) {
        int idx = s + i;
        int d = (idx < N_TILES) ? deg[idx] : 0;
        v[i] = sum;
        sum += d;
    }
    int lane = t & 63, wid = t >> 6;
    int inc = sum;
    #pragma unroll
    for (int d = 1; d < 64; d <<= 1) {
        int o = __shfl_up(inc, d);
        if (lane >= d) inc += o;
    }
    if (lane == 63) wsum[wid] = inc;
    __syncthreads();
    if (t < 16) {
        int w = wsum[t];
        int winc = w;
        #pragma unroll
        for (int d = 1; d < 16; d <<= 1) {
            int o = __shfl_up(winc, d);
            if (t >= d) winc += o;
        }
        wsum[t] = winc - w;  // exclusive wave offset
    }
    __syncthreads();
    int base = wsum[wid] + (inc - sum);  // exclusive prefix for this thread
    #pragma unroll
    for (int i = 0; i < CH; ++i) {
        int idx = s + i;
        if (idx < N_TILES) { off[idx] = base + v[i]; cursor[idx] = base + v[i]; }
    }
    if (t == 1023) off[N_TILES] = base + sum;
}

__global__ void scatter_kernel(const int* __restrict__ ei, int* __restrict__ cursor,
                               int* __restrict__ csr) {
    int e = blockIdx.x * blockDim.x + threadIdx.x;
    if (e < N_EDGES) {
        int p = atomicAdd(&cursor[ei[e] >> 3], 1);
        csr[p] = e;
    }
}

// ---------------- fused per-tile Z + edge message kernel ----------------
// Z[v][k][l] = sum_f x[v,f] * W2[k, f*32+l]    (stored bf16 in LDS)
// B[v][l]    = sum_f x[v,f] * b2[f*32+l]
// h_e[k]     = relu(b1[k] + sum_f ea[e,f] * W1[f,k])
// msg_e[l]   = B[src] + sum_k h_e[k] * Z[src][k][l]
__global__ __launch_bounds__(256) void fused_edge_kernel(
    const float* __restrict__ x, const int* __restrict__ ei,
    const float* __restrict__ ea, const float* __restrict__ W1,
    const float* __restrict__ b1, const float* __restrict__ W2,
    const float* __restrict__ b2, const int* __restrict__ off,
    const int* __restrict__ csr, float* __restrict__ agg)
{
    __shared__ __attribute__((aligned(16))) float xsT[F_IN * NT];       // [f][n]  1 KB
    __shared__ __attribute__((aligned(16))) float W1s[F_EDGE * LATENT]; // [f][k]  2 KB
    __shared__ __attribute__((aligned(16))) float b1s[LATENT];
    __shared__ __attribute__((aligned(16))) ushort Zs[NT * LATENT * LATENT]; // [n][k][l] bf16 16 KB
    __shared__ __attribute__((aligned(16))) float Bs[NT * LATENT];      // [n][l]  1 KB

    int t = threadIdx.x;
    int v0 = blockIdx.x * NT;

    {
        int n = t >> 5, f = t & 31;
        xsT[f * NT + n] = x[(v0 + n) * F_IN + f];
        W1s[t] = W1[t];
        W1s[t + 256] = W1[t + 256];
        if (t < LATENT) b1s[t] = b1[t];
    }
    __syncthreads();

    // ---- Z phase: thread owns (k, l4); W2 element read exactly once per block
    {
        int k = t >> 3;
        int l4 = (t & 7) << 2;
        float4 acc[NT];
        #pragma unroll
        for (int n = 0; n < NT; ++n) acc[n] = make_float4(0.f, 0.f, 0.f, 0.f);
        #pragma unroll 4
        for (int f = 0; f < F_IN; ++f) {
            const float4 wv = *(const float4*)(W2 + k * (F_IN * LATENT) + f * LATENT + l4);
            const float4* xp = (const float4*)(xsT + f * NT);
            float4 xa = xp[0], xb = xp[1];
            const float xr[NT] = {xa.x, xa.y, xa.z, xa.w, xb.x, xb.y, xb.z, xb.w};
            #pragma unroll
            for (int n = 0; n < NT; ++n) {
                acc[n].x += xr[n] * wv.x;
                acc[n].y += xr[n] * wv.y;
                acc[n].z += xr[n] * wv.z;
                acc[n].w += xr[n] * wv.w;
            }
        }
        #pragma unroll
        for (int n = 0; n < NT; ++n) {
            union { ushort u[4]; uint2 q; } pk;
            pk.u[0] = f2bf(acc[n].x); pk.u[1] = f2bf(acc[n].y);
            pk.u[2] = f2bf(acc[n].z); pk.u[3] = f2bf(acc[n].w);
            *(uint2*)(Zs + n * (LATENT * LATENT) + k * LATENT + l4) = pk.q;
        }
    }
    if (t < NT * 8) {
        int n = t >> 3; int l4 = (t & 7) << 2;
        float4 b = make_float4(0.f, 0.f, 0.f, 0.f);
        for (int f = 0; f < F_IN; ++f) {
            float xf = xsT[f * NT + n];
            const float4 bb = *(const float4*)(b2 + f * LATENT + l4);
            b.x += xf * bb.x; b.y += xf * bb.y; b.z += xf * bb.z; b.w += xf * bb.w;
        }
        *(float4*)(Bs + n * LATENT + l4) = b;
    }
    __syncthreads();

    // ---- edge phase: each wave does 2 edges/iter (one per 32-lane half)
    int estart = off[blockIdx.x];
    int eend = off[blockIdx.x + 1];
    int wave = t >> 6, lane = t & 63;
    int half = lane >> 5;
    int l = lane & 31;
    for (int p0 = estart + wave * 2; p0 < eend; p0 += 8) {
        int p = p0 + half;
        if (p < eend) {
            int e = csr[p];
            int s = ei[e];
            int n = s - v0;
            int d = ei[N_EDGES + e];
            const float* eap = ea + e * F_EDGE;
            float h = b1s[l];
            #pragma unroll
            for (int f = 0; f < F_EDGE; ++f) h += eap[f] * W1s[f * LATENT + l];
            h = fmaxf(h, 0.0f);
            float m = Bs[n * LATENT + l];
            const ushort* zp = Zs + n * (LATENT * LATENT) + l;
            #pragma unroll
            for (int kk = 0; kk < LATENT; ++kk) {
                float hk = __shfl(h, (lane & 32) | kk);
                m += hk * bf2f(zp[kk * LATENT]);
            }
            atomicAdd(&agg[d * LATENT + l], m);
        }
    }
}

// ---------------- node update + global mean pool ----------------
__global__ void nodepool_kernel(const float* __restrict__ x, const float* __restrict__ agg,
                                const float* __restrict__ root, const float* __restrict__ cbias,
                                const int* __restrict__ batch, float* __restrict__ pool,
                                float* __restrict__ pcnt)
{
    int t = blockIdx.x * blockDim.x + threadIdx.x;
    int v = t >> 5, l = t & 31;
    if (v >= N_NODES) return;
    float a = agg[v * LATENT + l] + cbias[l];
    #pragma unroll 8
    for (int f = 0; f < F_IN; ++f) a += x[v * F_IN + f] * root[f * LATENT + l];
    a = fmaxf(a, 0.0f);
    int g = batch[v];
    atomicAdd(&pool[g * LATENT + l], a);
    if (l == 0) atomicAdd(&pcnt[g], 1.0f);
}

// ---------------- final FC ----------------
__global__ void final_kernel(const float* __restrict__ pool, const float* __restrict__ pcnt,
                             const float* __restrict__ fcw, const float* __restrict__ fcb,
                             float* __restrict__ out)
{
    int t = blockIdx.x * blockDim.x + threadIdx.x;
    int g = t >> 7, j = t & 127;
    if (g >= N_GRAPHS) return;
    float inv = 1.0f / fmaxf(pcnt[g], 1.0f);
    float o = fcb[j];
    #pragma unroll 8
    for (int l = 0; l < LATENT; ++l) {
        float pv = fmaxf(pool[g * LATENT + l] * inv, 0.0f);
        o += pv * fcw[l * EMBED + j];
    }
    out[g * EMBED + j] = o;
}

extern "C" void kernel_launch(void* const* d_in, const int* in_sizes, int n_in,
                              void* d_out, int out_size, void* d_ws, size_t ws_size,
                              hipStream_t stream)
{
    const float* x     = (const float*)d_in[0];
    const int*   ei    = (const int*)d_in[1];
    const float* ea    = (const float*)d_in[2];
    const int*   batch = (const int*)d_in[3];
    const float* W1    = (const float*)d_in[4];
    const float* b1    = (const float*)d_in[5];
    const float* W2    = (const float*)d_in[6];
    const float* b2    = (const float*)d_in[7];
    const float* root  = (const float*)d_in[8];
    const float* cb    = (const float*)d_in[9];
    const float* fcw   = (const float*)d_in[10];
    const float* fcb   = (const float*)d_in[11];
    float* out = (float*)d_out;

    char* w = (char*)d_ws;
    auto alloc = [&](size_t bytes) {
        char* p = w;
        w += (bytes + 255) & ~size_t(255);
        return p;
    };
    int*   deg    = (int*)alloc(N_TILES * 4);
    int*   off    = (int*)alloc((N_TILES + 1) * 4);
    int*   cursor = (int*)alloc(N_TILES * 4);
    int*   csr    = (int*)alloc(N_EDGES * 4);
    float* agg    = (float*)alloc((size_t)N_NODES * LATENT * 4);
    float* pool   = (float*)alloc(N_GRAPHS * LATENT * 4);
    float* pcnt   = (float*)alloc(N_GRAPHS * 4);

    zero_kernel<<<(N_NODES * LATENT / 4 + 255) / 256, 256, 0, stream>>>(
        deg, (float4*)agg, pool, pcnt);
    hist_kernel<<<(N_EDGES + 255) / 256, 256, 0, stream>>>(ei, deg);
    scan_kernel<<<1, 1024, 0, stream>>>(deg, off, cursor);
    scatter_kernel<<<(N_EDGES + 255) / 256, 256, 0, stream>>>(ei, cursor, csr);
    fused_edge_kernel<<<N_TILES, 256, 0, stream>>>(x, ei, ea, W1, b1, W2, b2, off, csr, agg);
    nodepool_kernel<<<(N_NODES * LATENT + 255) / 256, 256, 0, stream>>>(x, agg, root, cb, batch, pool, pcnt);
    final_kernel<<<(N_GRAPHS * EMBED + 255) / 256, 256, 0, stream>>>(pool, pcnt, fcw, fcb, out);
}

// Round 3
// 188.817 us; speedup vs baseline: 1.8288x; 1.2305x over previous
//
#include <hip/hip_runtime.h>
#include <hip/hip_bf16.h>

#define N_NODES 50000
#define N_EDGES 250000
#define N_GRAPHS 512
#define F_IN 32
#define F_EDGE 16
#define LATENT 32
#define EMBED 128
#define E_BLK 128
#define N_EBLK ((N_EDGES + E_BLK - 1) / E_BLK)  // 1954

typedef unsigned short ushort;
typedef __attribute__((ext_vector_type(8))) short short8;
typedef __attribute__((ext_vector_type(4))) float f32x4;

union U16x8 { short8 s8; ushort u[8]; };

__device__ inline ushort f2bf(float f) {
    __hip_bfloat16 b = __float2bfloat16(f);
    return *reinterpret_cast<ushort*>(&b);
}
__device__ inline float bf2f(ushort u) {
    __hip_bfloat16 b;
    *reinterpret_cast<ushort*>(&b) = u;
    return __bfloat162float(b);
}

// ---------------- prep: zero accumulators + build W2^T bf16 [32 l][1024 kk] ----------------
// W2 flat idx = k*1024 + f*32 + l = (k*32+f)*32 + l = kk*32 + l  →  W2T[l][kk] = W2.flat[kk*32+l]
__global__ void prep_kernel(const float* __restrict__ W2, ushort* __restrict__ W2T,
                            float4* __restrict__ agg4, float* __restrict__ pool,
                            float* __restrict__ pcnt) {
    int i = blockIdx.x * blockDim.x + threadIdx.x;
    if (i < (N_NODES * LATENT) / 4) agg4[i] = make_float4(0.f, 0.f, 0.f, 0.f);
    if (i < 32 * 1024) {
        int kk = i >> 5, l = i & 31;
        W2T[l * 1024 + kk] = f2bf(W2[i]);   // read coalesced
    }
    if (i < N_GRAPHS * LATENT) pool[i] = 0.f;
    if (i < N_GRAPHS) pcnt[i] = 0.f;
}

// ---------------- edge kernel: MSG[E x 32] = G[E x 1024] @ W2v[1024 x 32] ----------------
// G[e, k*32+f] = h[e,k] * x[src_e, f]  built implicitly in registers.
// MFMA 16x16x32 bf16: A row i = lane&15, k = (lane>>4)*8+j; B col j = lane&15, same k;
//                     D col j = lane&15, row i = (lane>>4)*4 + reg.
__global__ __launch_bounds__(256) void edge_mfma_kernel(
    const float* __restrict__ x, const int* __restrict__ ei,
    const float* __restrict__ ea, const float* __restrict__ W1,
    const float* __restrict__ b1, const ushort* __restrict__ W2T,
    float* __restrict__ agg)
{
    __shared__ __attribute__((aligned(16))) ushort Hs[E_BLK * LATENT]; // 8KB; row=edge (64B), swz ^((row&3)<<4)
    __shared__ __attribute__((aligned(16))) ushort W2q[32 * 256];      // 16KB; row=j (512B), swz ^((j&7)<<4)
    __shared__ int srcs[E_BLK];

    const int t = threadIdx.x;
    const int e0 = blockIdx.x * E_BLK;
    const int wv = t >> 6, lane = t & 63;
    const int g = lane >> 4, j16 = lane & 15;

    if (t < E_BLK) {
        int e = e0 + t; if (e >= N_EDGES) e = N_EDGES - 1;
        srcs[t] = ei[e];
    }

    // ---- H = relu(ea @ W1 + b1) via K-padded MFMA (f>=16 lanes hold zeros)
    short8 zero8 = (short8){0, 0, 0, 0, 0, 0, 0, 0};
    short8 bw[2];
    #pragma unroll
    for (int nt = 0; nt < 2; ++nt) {
        U16x8 tmp;
        #pragma unroll
        for (int b = 0; b < 8; ++b) {
            float w = (g < 2) ? W1[(8 * g + b) * LATENT + nt * 16 + j16] : 0.f;
            tmp.u[b] = f2bf(w);
        }
        bw[nt] = tmp.s8;
    }
    float b1v[2] = { b1[j16], b1[16 + j16] };

    #pragma unroll
    for (int mt = 0; mt < 2; ++mt) {
        int mtg = 2 * wv + mt;
        int rowA = mtg * 16 + j16;
        int e = e0 + rowA; if (e >= N_EDGES) e = N_EDGES - 1;
        U16x8 ae;
        if (g < 2) {
            const float4* p = (const float4*)(ea + (size_t)e * F_EDGE + 8 * g);
            float4 va = p[0], vb = p[1];
            ae.u[0] = f2bf(va.x); ae.u[1] = f2bf(va.y); ae.u[2] = f2bf(va.z); ae.u[3] = f2bf(va.w);
            ae.u[4] = f2bf(vb.x); ae.u[5] = f2bf(vb.y); ae.u[6] = f2bf(vb.z); ae.u[7] = f2bf(vb.w);
        } else ae.s8 = zero8;
        #pragma unroll
        for (int nt = 0; nt < 2; ++nt) {
            f32x4 hacc = (f32x4){0.f, 0.f, 0.f, 0.f};
            hacc = __builtin_amdgcn_mfma_f32_16x16x32_bf16(ae.s8, bw[nt], hacc, 0, 0, 0);
            #pragma unroll
            for (int v = 0; v < 4; ++v) {
                int rowD = mtg * 16 + 4 * g + v;
                int col = nt * 16 + j16;
                float hval = fmaxf(hacc[v] + b1v[nt], 0.f);
                int byteo = (rowD * 64 + col * 2) ^ ((rowD & 3) << 4);
                *(ushort*)((char*)Hs + byteo) = f2bf(hval);
            }
        }
    }
    __syncthreads();

    // ---- x fragments (fp32, reused across all K)
    f32x4 acc[2][2];
    #pragma unroll
    for (int a = 0; a < 2; ++a)
        #pragma unroll
        for (int b = 0; b < 2; ++b) acc[a][b] = (f32x4){0.f, 0.f, 0.f, 0.f};

    float xf[2][8];
    #pragma unroll
    for (int mt = 0; mt < 2; ++mt) {
        int row = (2 * wv + mt) * 16 + j16;
        int src = srcs[row];
        const float4* p = (const float4*)(x + (size_t)src * F_IN + 8 * g);
        float4 va = p[0], vb = p[1];
        xf[mt][0] = va.x; xf[mt][1] = va.y; xf[mt][2] = va.z; xf[mt][3] = va.w;
        xf[mt][4] = vb.x; xf[mt][5] = vb.y; xf[mt][6] = vb.z; xf[mt][7] = vb.w;
    }

    // ---- K loop: 4 quarters of 256 kk, W2T staged per quarter (XOR-swizzled)
    for (int q = 0; q < 4; ++q) {
        if (q) __syncthreads();
        #pragma unroll
        for (int c = 0; c < 4; ++c) {
            int ch = c * 256 + t;
            int lbyte = ch * 16;
            int jrow = lbyte >> 9;
            int off = lbyte & 511;
            short8 val = *(const short8*)((const char*)W2T + jrow * 2048 + q * 512 + off);
            *(short8*)((char*)W2q + jrow * 512 + (off ^ ((jrow & 7) << 4))) = val;
        }
        __syncthreads();

        U16x8 hu[2];
        #pragma unroll
        for (int mt = 0; mt < 2; ++mt) {
            int row = (2 * wv + mt) * 16 + j16;
            int byteo = (row * 64 + q * 16) ^ ((row & 3) << 4);
            hu[mt].s8 = *(const short8*)((const char*)Hs + byteo);
        }

        #pragma unroll
        for (int kst = 0; kst < 8; ++kst) {
            int kb = kst * 64 + g * 16;
            short8 bf0 = *(const short8*)((const char*)W2q + j16 * 512 + (kb ^ ((j16 & 7) << 4)));
            short8 bf1 = *(const short8*)((const char*)W2q + (16 + j16) * 512 + (kb ^ ((j16 & 7) << 4)));
            #pragma unroll
            for (int mt = 0; mt < 2; ++mt) {
                float hk = bf2f(hu[mt].u[kst]);
                U16x8 af;
                #pragma unroll
                for (int b = 0; b < 8; ++b) af.u[b] = f2bf(hk * xf[mt][b]);
                acc[mt][0] = __builtin_amdgcn_mfma_f32_16x16x32_bf16(af.s8, bf0, acc[mt][0], 0, 0, 0);
                acc[mt][1] = __builtin_amdgcn_mfma_f32_16x16x32_bf16(af.s8, bf1, acc[mt][1], 0, 0, 0);
            }
        }
    }

    // ---- scatter-add to agg[dst]
    #pragma unroll
    for (int mt = 0; mt < 2; ++mt) {
        int rowb = (2 * wv + mt) * 16 + 4 * g;
        #pragma unroll
        for (int v = 0; v < 4; ++v) {
            int e = e0 + rowb + v;
            if (e < N_EDGES) {
                int dst = ei[N_EDGES + e];
                atomicAdd(&agg[(size_t)dst * LATENT + j16],      acc[mt][0][v]);
                atomicAdd(&agg[(size_t)dst * LATENT + 16 + j16], acc[mt][1][v]);
            }
        }
    }
}

// ---------------- b2 term: msg_e += x[src_e] @ reshape(b2,[F_IN,LATENT]) ----------------
// (b2 is zeros in the given data, but honor it exactly; cost ~few µs)
__global__ void b2fix_kernel(const float* __restrict__ x, const int* __restrict__ ei,
                             const float* __restrict__ b2, float* __restrict__ agg)
{
    __shared__ float b2s[F_IN * LATENT];
    int t = threadIdx.x;
    b2s[t] = b2[t];
    b2s[t + 256] = b2[t + 256];
    b2s[t + 512] = b2[t + 512];
    b2s[t + 768] = b2[t + 768];
    __syncthreads();
    // quick uniform-zero check to skip work (b2 is an input; exact either way)
    int e2 = blockIdx.x * (blockDim.x / 32) + (t >> 5);
    int l = t & 31;
    if (e2 >= N_EDGES) return;
    int s = ei[e2];
    int d = ei[N_EDGES + e2];
    float m = 0.f;
    #pragma unroll 8
    for (int f = 0; f < F_IN; ++f) m += x[s * F_IN + f] * b2s[f * LATENT + l];
    if (m != 0.f) atomicAdd(&agg[(size_t)d * LATENT + l], m);
}

// ---------------- node update + global mean pool ----------------
__global__ void nodepool_kernel(const float* __restrict__ x, const float* __restrict__ agg,
                                const float* __restrict__ root, const float* __restrict__ cbias,
                                const int* __restrict__ batch, float* __restrict__ pool,
                                float* __restrict__ pcnt)
{
    int t = blockIdx.x * blockDim.x + threadIdx.x;
    int v = t >> 5, l = t & 31;
    if (v >= N_NODES) return;
    float a = agg[v * LATENT + l] + cbias[l];
    #pragma unroll 8
    for (int f = 0; f < F_IN; ++f) a += x[v * F_IN + f] * root[f * LATENT + l];
    a = fmaxf(a, 0.0f);
    int gr = batch[v];
    atomicAdd(&pool[gr * LATENT + l], a);
    if (l == 0) atomicAdd(&pcnt[gr], 1.0f);
}

// ---------------- final FC ----------------
__global__ void final_kernel(const float* __restrict__ pool, const float* __restrict__ pcnt,
                             const float* __restrict__ fcw, const float* __restrict__ fcb,
                             float* __restrict__ out)
{
    int t = blockIdx.x * blockDim.x + threadIdx.x;
    int gr = t >> 7, j = t & 127;
    if (gr >= N_GRAPHS) return;
    float inv = 1.0f / fmaxf(pcnt[gr], 1.0f);
    float o = fcb[j];
    #pragma unroll 8
    for (int l = 0; l < LATENT; ++l) {
        float pv = fmaxf(pool[gr * LATENT + l] * inv, 0.0f);
        o += pv * fcw[l * EMBED + j];
    }
    out[gr * EMBED + j] = o;
}

extern "C" void kernel_launch(void* const* d_in, const int* in_sizes, int n_in,
                              void* d_out, int out_size, void* d_ws, size_t ws_size,
                              hipStream_t stream)
{
    const float* x     = (const float*)d_in[0];
    const int*   ei    = (const int*)d_in[1];
    const float* ea    = (const float*)d_in[2];
    const int*   batch = (const int*)d_in[3];
    const float* W1    = (const float*)d_in[4];
    const float* b1    = (const float*)d_in[5];
    const float* W2    = (const float*)d_in[6];
    const float* b2    = (const float*)d_in[7];
    const float* root  = (const float*)d_in[8];
    const float* cb    = (const float*)d_in[9];
    const float* fcw   = (const float*)d_in[10];
    const float* fcb   = (const float*)d_in[11];
    float* out = (float*)d_out;

    char* w = (char*)d_ws;
    auto alloc = [&](size_t bytes) {
        char* p = w;
        w += (bytes + 255) & ~size_t(255);
        return p;
    };
    ushort* W2T  = (ushort*)alloc(32 * 1024 * 2);
    float*  agg  = (float*)alloc((size_t)N_NODES * LATENT * 4);
    float*  pool = (float*)alloc(N_GRAPHS * LATENT * 4);
    float*  pcnt = (float*)alloc(N_GRAPHS * 4);

    prep_kernel<<<1563, 256, 0, stream>>>(W2, W2T, (float4*)agg, pool, pcnt);
    edge_mfma_kernel<<<N_EBLK, 256, 0, stream>>>(x, ei, ea, W1, b1, W2T, agg);
    b2fix_kernel<<<(N_EDGES * 32 + 255) / 256, 256, 0, stream>>>(x, ei, b2, agg);
    nodepool_kernel<<<(N_NODES * LATENT + 255) / 256, 256, 0, stream>>>(x, agg, root, cb, batch, pool, pcnt);
    final_kernel<<<(N_GRAPHS * EMBED + 255) / 256, 256, 0, stream>>>(pool, pcnt, fcw, fcb, out);
}

// Round 4
// 82.193 us; speedup vs baseline: 4.2011x; 2.2972x over previous
//
#include <hip/hip_runtime.h>
#include <hip/hip_bf16.h>

#define N_NODES 50000
#define N_EDGES 250000
#define N_GRAPHS 512
#define F_IN 32
#define F_EDGE 16
#define LATENT 32
#define EMBED 128
#define E_BLK 128
#define N_EBLK ((N_EDGES + E_BLK - 1) / E_BLK)  // 1954
#define KW 1056                                  // W2T row length: 1024 + 32 (b2 fold)

typedef unsigned short ushort;
typedef __attribute__((ext_vector_type(8))) short short8;
typedef __attribute__((ext_vector_type(4))) float f32x4;

union U16x8 { short8 s8; ushort u[8]; };

__device__ inline ushort f2bf(float f) {
    __hip_bfloat16 b = __float2bfloat16(f);
    return *reinterpret_cast<ushort*>(&b);
}
__device__ inline float bf2f(ushort u) {
    __hip_bfloat16 b;
    *reinterpret_cast<ushort*>(&b) = u;
    return __bfloat162float(b);
}

// ---------------- prep: zero accumulators + build W2T bf16 [32 l][1056 kk] ----------------
// kk < 1024:  W2 flat idx = kk*32 + l  ->  W2T[l][kk] = W2.flat[kk*32+l]
// kk >= 1024: W2T[l][1024+f] = b2[f*32+l]   (b2 folded as 32 extra K rows, h == 1)
__global__ void prep_kernel(const float* __restrict__ W2, const float* __restrict__ b2,
                            ushort* __restrict__ W2T, float4* __restrict__ agg4,
                            float* __restrict__ pool, float* __restrict__ pcnt) {
    int i = blockIdx.x * blockDim.x + threadIdx.x;
    if (i < (N_NODES * LATENT) / 4) agg4[i] = make_float4(0.f, 0.f, 0.f, 0.f);
    if (i < 32 * 1024) {
        int kk = i >> 5, l = i & 31;
        W2T[l * KW + kk] = f2bf(W2[i]);   // coalesced read
    }
    if (i < 1024) {
        int f = i >> 5, l = i & 31;
        W2T[l * KW + 1024 + f] = f2bf(b2[i]);
    }
    if (i < N_GRAPHS * LATENT) pool[i] = 0.f;
    if (i < N_GRAPHS) pcnt[i] = 0.f;
}

// ---------------- edge kernel: MSG[E x 32] = G[E x 1056] @ W2T^T ----------------
// G[e, k*32+f] = h[e,k] * x[src_e, f]  (k<32) ;  G[e, 1024+f] = x[src_e, f]
// MFMA 16x16x32 bf16 fragments: A row i = lane&15, k = (lane>>4)*8+b;
//                               D col j = lane&15, row i = (lane>>4)*4 + reg.
__global__ __launch_bounds__(256) void edge_mfma_kernel(
    const float* __restrict__ x, const int* __restrict__ ei,
    const float* __restrict__ ea, const float* __restrict__ W1,
    const float* __restrict__ b1, const ushort* __restrict__ W2T,
    float* __restrict__ agg)
{
    __shared__ __attribute__((aligned(16))) ushort Hs[E_BLK * LATENT]; // 8KB; row=edge (64B), swz ^((row&3)<<4)
    __shared__ __attribute__((aligned(16))) ushort W2q[32 * 256];      // 16KB; row=j (512B), swz ^((j&7)<<4)
    __shared__ int srcs[E_BLK];

    const int t = threadIdx.x;
    const int e0 = blockIdx.x * E_BLK;
    const int wv = t >> 6, lane = t & 63;
    const int g = lane >> 4, j16 = lane & 15;

    if (t < E_BLK) {
        int e = e0 + t; if (e >= N_EDGES) e = N_EDGES - 1;
        srcs[t] = ei[e];
    }

    // ---- H = relu(ea @ W1 + b1) via K-padded MFMA (f>=16 lanes hold zeros)
    short8 zero8 = (short8){0, 0, 0, 0, 0, 0, 0, 0};
    short8 bw[2];
    #pragma unroll
    for (int nt = 0; nt < 2; ++nt) {
        U16x8 tmp;
        #pragma unroll
        for (int b = 0; b < 8; ++b) {
            float w = (g < 2) ? W1[(8 * g + b) * LATENT + nt * 16 + j16] : 0.f;
            tmp.u[b] = f2bf(w);
        }
        bw[nt] = tmp.s8;
    }
    float b1v[2] = { b1[j16], b1[16 + j16] };

    // ---- b2-extension B fragments (kk = 1024 + 8g + b), 16B aligned (2112 = 132*16)
    short8 bx0 = *(const short8*)(W2T + j16 * KW + 1024 + 8 * g);
    short8 bx1 = *(const short8*)(W2T + (16 + j16) * KW + 1024 + 8 * g);

    #pragma unroll
    for (int mt = 0; mt < 2; ++mt) {
        int mtg = 2 * wv + mt;
        int rowA = mtg * 16 + j16;
        int e = e0 + rowA; if (e >= N_EDGES) e = N_EDGES - 1;
        U16x8 ae;
        if (g < 2) {
            const float4* p = (const float4*)(ea + (size_t)e * F_EDGE + 8 * g);
            float4 va = p[0], vb = p[1];
            ae.u[0] = f2bf(va.x); ae.u[1] = f2bf(va.y); ae.u[2] = f2bf(va.z); ae.u[3] = f2bf(va.w);
            ae.u[4] = f2bf(vb.x); ae.u[5] = f2bf(vb.y); ae.u[6] = f2bf(vb.z); ae.u[7] = f2bf(vb.w);
        } else ae.s8 = zero8;
        #pragma unroll
        for (int nt = 0; nt < 2; ++nt) {
            f32x4 hacc = (f32x4){0.f, 0.f, 0.f, 0.f};
            hacc = __builtin_amdgcn_mfma_f32_16x16x32_bf16(ae.s8, bw[nt], hacc, 0, 0, 0);
            #pragma unroll
            for (int v = 0; v < 4; ++v) {
                int rowD = mtg * 16 + 4 * g + v;
                int col = nt * 16 + j16;
                float hval = fmaxf(hacc[v] + b1v[nt], 0.f);
                int byteo = (rowD * 64 + col * 2) ^ ((rowD & 3) << 4);
                *(ushort*)((char*)Hs + byteo) = f2bf(hval);
            }
        }
    }
    __syncthreads();

    // ---- x fragments (fp32, reused across all K)
    f32x4 acc[2][2];
    #pragma unroll
    for (int a = 0; a < 2; ++a)
        #pragma unroll
        for (int b = 0; b < 2; ++b) acc[a][b] = (f32x4){0.f, 0.f, 0.f, 0.f};

    float xf[2][8];
    #pragma unroll
    for (int mt = 0; mt < 2; ++mt) {
        int row = (2 * wv + mt) * 16 + j16;
        int src = srcs[row];
        const float4* p = (const float4*)(x + (size_t)src * F_IN + 8 * g);
        float4 va = p[0], vb = p[1];
        xf[mt][0] = va.x; xf[mt][1] = va.y; xf[mt][2] = va.z; xf[mt][3] = va.w;
        xf[mt][4] = vb.x; xf[mt][5] = vb.y; xf[mt][6] = vb.z; xf[mt][7] = vb.w;
    }

    // ---- b2-extension K-step: A = x fragment directly (h == 1)
    #pragma unroll
    for (int mt = 0; mt < 2; ++mt) {
        U16x8 axf;
        #pragma unroll
        for (int b = 0; b < 8; ++b) axf.u[b] = f2bf(xf[mt][b]);
        acc[mt][0] = __builtin_amdgcn_mfma_f32_16x16x32_bf16(axf.s8, bx0, acc[mt][0], 0, 0, 0);
        acc[mt][1] = __builtin_amdgcn_mfma_f32_16x16x32_bf16(axf.s8, bx1, acc[mt][1], 0, 0, 0);
    }

    // ---- K loop: 4 quarters of 256 kk, W2T staged per quarter (XOR-swizzled)
    for (int q = 0; q < 4; ++q) {
        if (q) __syncthreads();
        #pragma unroll
        for (int c = 0; c < 4; ++c) {
            int ch = c * 256 + t;
            int lbyte = ch * 16;
            int jrow = lbyte >> 9;
            int off = lbyte & 511;
            short8 val = *(const short8*)((const char*)W2T + jrow * (KW * 2) + q * 512 + off);
            *(short8*)((char*)W2q + jrow * 512 + (off ^ ((jrow & 7) << 4))) = val;
        }
        __syncthreads();

        U16x8 hu[2];
        #pragma unroll
        for (int mt = 0; mt < 2; ++mt) {
            int row = (2 * wv + mt) * 16 + j16;
            int byteo = (row * 64 + q * 16) ^ ((row & 3) << 4);
            hu[mt].s8 = *(const short8*)((const char*)Hs + byteo);
        }

        #pragma unroll
        for (int kst = 0; kst < 8; ++kst) {
            int kb = kst * 64 + g * 16;
            short8 bf0 = *(const short8*)((const char*)W2q + j16 * 512 + (kb ^ ((j16 & 7) << 4)));
            short8 bf1 = *(const short8*)((const char*)W2q + (16 + j16) * 512 + (kb ^ ((j16 & 7) << 4)));
            #pragma unroll
            for (int mt = 0; mt < 2; ++mt) {
                float hk = bf2f(hu[mt].u[kst]);
                U16x8 af;
                #pragma unroll
                for (int b = 0; b < 8; ++b) af.u[b] = f2bf(hk * xf[mt][b]);
                acc[mt][0] = __builtin_amdgcn_mfma_f32_16x16x32_bf16(af.s8, bf0, acc[mt][0], 0, 0, 0);
                acc[mt][1] = __builtin_amdgcn_mfma_f32_16x16x32_bf16(af.s8, bf1, acc[mt][1], 0, 0, 0);
            }
        }
    }

    // ---- scatter-add to agg[dst]
    #pragma unroll
    for (int mt = 0; mt < 2; ++mt) {
        int rowb = (2 * wv + mt) * 16 + 4 * g;
        #pragma unroll
        for (int v = 0; v < 4; ++v) {
            int e = e0 + rowb + v;
            if (e < N_EDGES) {
                int dst = ei[N_EDGES + e];
                atomicAdd(&agg[(size_t)dst * LATENT + j16],      acc[mt][0][v]);
                atomicAdd(&agg[(size_t)dst * LATENT + 16 + j16], acc[mt][1][v]);
            }
        }
    }
}

// ---------------- node update + global mean pool ----------------
// Lane l owns output column l; each 32-lane group walks VN consecutive nodes with a
// running per-graph partial sum (batch is sorted -> ~1 atomic flush per graph-run).
#define VN 8
__global__ __launch_bounds__(256) void nodepool_kernel(
    const float* __restrict__ x, const float* __restrict__ agg,
    const float* __restrict__ root, const float* __restrict__ cbias,
    const int* __restrict__ batch, float* __restrict__ pool,
    float* __restrict__ pcnt)
{
    int t = threadIdx.x;
    int l = t & 31;
    int stripe = t >> 5;  // 0..7
    int v0 = (blockIdx.x * 8 + stripe) * VN;
    float rc[F_IN];
    #pragma unroll
    for (int f = 0; f < F_IN; ++f) rc[f] = root[f * LATENT + l];
    float cbl = cbias[l];

    float sum = 0.f, cnt = 0.f;
    int gcur = -1;
    for (int i = 0; i < VN; ++i) {
        int v = v0 + i;
        if (v >= N_NODES) break;
        int g = batch[v];
        if (g != gcur) {
            if (gcur >= 0) {
                atomicAdd(&pool[gcur * LATENT + l], sum);
                if (l == 0) atomicAdd(&pcnt[gcur], cnt);
            }
            gcur = g; sum = 0.f; cnt = 0.f;
        }
        float xv = x[(size_t)v * F_IN + l];     // coalesced 128B per 32-lane group
        float a = agg[(size_t)v * LATENT + l] + cbl;
        #pragma unroll
        for (int f = 0; f < F_IN; ++f) {
            float xfv = __shfl(xv, (t & 32) | f);
            a += xfv * rc[f];
        }
        sum += fmaxf(a, 0.f);
        cnt += 1.f;
    }
    if (gcur >= 0) {
        atomicAdd(&pool[gcur * LATENT + l], sum);
        if (l == 0) atomicAdd(&pcnt[gcur], cnt);
    }
}

// ---------------- final FC ----------------
__global__ void final_kernel(const float* __restrict__ pool, const float* __restrict__ pcnt,
                             const float* __restrict__ fcw, const float* __restrict__ fcb,
                             float* __restrict__ out)
{
    int t = blockIdx.x * blockDim.x + threadIdx.x;
    int gr = t >> 7, j = t & 127;
    if (gr >= N_GRAPHS) return;
    float inv = 1.0f / fmaxf(pcnt[gr], 1.0f);
    float o = fcb[j];
    #pragma unroll 8
    for (int l = 0; l < LATENT; ++l) {
        float pv = fmaxf(pool[gr * LATENT + l] * inv, 0.0f);
        o += pv * fcw[l * EMBED + j];
    }
    out[gr * EMBED + j] = o;
}

extern "C" void kernel_launch(void* const* d_in, const int* in_sizes, int n_in,
                              void* d_out, int out_size, void* d_ws, size_t ws_size,
                              hipStream_t stream)
{
    const float* x     = (const float*)d_in[0];
    const int*   ei    = (const int*)d_in[1];
    const float* ea    = (const float*)d_in[2];
    const int*   batch = (const int*)d_in[3];
    const float* W1    = (const float*)d_in[4];
    const float* b1    = (const float*)d_in[5];
    const float* W2    = (const float*)d_in[6];
    const float* b2    = (const float*)d_in[7];
    const float* root  = (const float*)d_in[8];
    const float* cb    = (const float*)d_in[9];
    const float* fcw   = (const float*)d_in[10];
    const float* fcb   = (const float*)d_in[11];
    float* out = (float*)d_out;

    char* w = (char*)d_ws;
    auto alloc = [&](size_t bytes) {
        char* p = w;
        w += (bytes + 255) & ~size_t(255);
        return p;
    };
    ushort* W2T  = (ushort*)alloc((size_t)32 * KW * 2);
    float*  agg  = (float*)alloc((size_t)N_NODES * LATENT * 4);
    float*  pool = (float*)alloc(N_GRAPHS * LATENT * 4);
    float*  pcnt = (float*)alloc(N_GRAPHS * 4);

    prep_kernel<<<1563, 256, 0, stream>>>(W2, b2, W2T, (float4*)agg, pool, pcnt);
    edge_mfma_kernel<<<N_EBLK, 256, 0, stream>>>(x, ei, ea, W1, b1, W2T, agg);
    nodepool_kernel<<<(N_NODES + 8 * VN - 1) / (8 * VN), 256, 0, stream>>>(
        x, agg, root, cb, batch, pool, pcnt);
    final_kernel<<<(N_GRAPHS * EMBED + 255) / 256, 256, 0, stream>>>(pool, pcnt, fcw, fcb, out);
}

// Round 5
// 77.573 us; speedup vs baseline: 4.4514x; 1.0596x over previous
//
#include <hip/hip_runtime.h>

#define N_NODES 50000
#define N_EDGES 250000
#define N_GRAPHS 512
#define F_IN 32
#define F_EDGE 16
#define LATENT 32
#define EMBED 128
#define E_BLK 128
#define N_EBLK ((N_EDGES + E_BLK - 1) / E_BLK)  // 1954
#define KW 1056                                  // W2T row length: 1024 + 32 (b2 fold)
#define HS_STRIDE 36                             // Hs2 row stride in dwords (16B aligned)

typedef unsigned short ushort;
typedef unsigned int uint;
typedef _Float16 half8v __attribute__((ext_vector_type(8)));
typedef _Float16 half2v __attribute__((ext_vector_type(2)));
typedef __attribute__((ext_vector_type(4))) float f32x4;

union UH8 { half8v h8; half2v h2[4]; ushort u[8]; uint q[4]; };
union UH2 { half2v h2; uint q; };

__device__ inline ushort f2h_bits(float f) {
    _Float16 h = (_Float16)f;
    return *reinterpret_cast<ushort*>(&h);
}

// ---------------- prep: zero agg/pool + x->f16 + W2T(f16) [32 l][1056 kk] ----------------
// kk < 1024:  W2T[l][kk] = W2.flat[kk*32 + l]
// kk >= 1024: W2T[l][1024+f] = b2[f*32 + l]    (b2 folded; paired with h == 1)
__global__ void prep_kernel(const float* __restrict__ x, const float* __restrict__ W2,
                            const float* __restrict__ b2, ushort* __restrict__ xh,
                            ushort* __restrict__ W2T, float4* __restrict__ agg4,
                            float* __restrict__ pool, float* __restrict__ pcnt) {
    int i = blockIdx.x * blockDim.x + threadIdx.x;
    if (i < (N_NODES * F_IN) / 4) {
        float4 v = ((const float4*)x)[i];
        union { ushort u[4]; uint2 q; } pk;
        pk.u[0] = f2h_bits(v.x); pk.u[1] = f2h_bits(v.y);
        pk.u[2] = f2h_bits(v.z); pk.u[3] = f2h_bits(v.w);
        ((uint2*)xh)[i] = pk.q;
    }
    if (i < (N_NODES * LATENT) / 4) agg4[i] = make_float4(0.f, 0.f, 0.f, 0.f);
    if (i < 32 * 1024) {
        int kk = i >> 5, l = i & 31;
        W2T[l * KW + kk] = f2h_bits(W2[i]);   // coalesced read
    }
    if (i < 1024) {
        int f = i >> 5, l = i & 31;
        W2T[l * KW + 1024 + f] = f2h_bits(b2[i]);
    }
    if (i < N_GRAPHS * LATENT) pool[i] = 0.f;
    if (i < N_GRAPHS) pcnt[i] = 0.f;
}

// ---------------- edge kernel: MSG[E x 32] = G[E x 1056] @ W2T^T  (f16 MFMA) ----------------
// G[e, k*32+f] = h[e,k] * x[src_e, f]  (k<32) ;  G[e, 1024+f] = x[src_e, f]
// MFMA 16x16x32: A row i = lane&15, k-slot = (lane>>4)*8+b;
//                D col j = lane&15, row i = (lane>>4)*4 + reg.
__global__ __launch_bounds__(256) void edge_mfma_kernel(
    const ushort* __restrict__ xh, const int* __restrict__ ei,
    const float* __restrict__ ea, const float* __restrict__ W1,
    const float* __restrict__ b1, const ushort* __restrict__ W2T,
    float* __restrict__ agg)
{
    __shared__ __attribute__((aligned(16))) uint Hs2[E_BLK * HS_STRIDE]; // {h,h} packed f16, 18KB
    __shared__ __attribute__((aligned(16))) ushort W2q[32 * 256];        // 16KB; row=j (512B), swz ^((j&7)<<4)

    const int t = threadIdx.x;
    const int e0 = blockIdx.x * E_BLK;
    const int wv = t >> 6, lane = t & 63;
    const int g = lane >> 4, j16 = lane & 15;

    // ---- H = relu(ea @ W1 + b1) via K-padded f16 MFMA (f>=16 lanes hold zeros)
    UH8 bw[2];
    #pragma unroll
    for (int nt = 0; nt < 2; ++nt) {
        #pragma unroll
        for (int b = 0; b < 8; ++b) {
            float w = (g < 2) ? W1[(8 * g + b) * LATENT + nt * 16 + j16] : 0.f;
            bw[nt].u[b] = f2h_bits(w);
        }
    }
    float b1v[2] = { b1[j16], b1[16 + j16] };

    #pragma unroll
    for (int mt = 0; mt < 2; ++mt) {
        int mtg = 2 * wv + mt;
        int rowA = mtg * 16 + j16;
        int e = e0 + rowA; if (e >= N_EDGES) e = N_EDGES - 1;
        UH8 ae;
        if (g < 2) {
            const float4* p = (const float4*)(ea + (size_t)e * F_EDGE + 8 * g);
            float4 va = p[0], vb = p[1];
            ae.u[0] = f2h_bits(va.x); ae.u[1] = f2h_bits(va.y);
            ae.u[2] = f2h_bits(va.z); ae.u[3] = f2h_bits(va.w);
            ae.u[4] = f2h_bits(vb.x); ae.u[5] = f2h_bits(vb.y);
            ae.u[6] = f2h_bits(vb.z); ae.u[7] = f2h_bits(vb.w);
        } else {
            ae.q[0] = 0; ae.q[1] = 0; ae.q[2] = 0; ae.q[3] = 0;
        }
        #pragma unroll
        for (int nt = 0; nt < 2; ++nt) {
            f32x4 hacc = (f32x4){0.f, 0.f, 0.f, 0.f};
            hacc = __builtin_amdgcn_mfma_f32_16x16x32_f16(ae.h8, bw[nt].h8, hacc, 0, 0, 0);
            #pragma unroll
            for (int v = 0; v < 4; ++v) {
                int rowD = mtg * 16 + 4 * g + v;
                int col = nt * 16 + j16;
                float hval = fmaxf(hacc[v] + b1v[nt], 0.f);
                uint hb = (uint)f2h_bits(hval);
                Hs2[rowD * HS_STRIDE + col] = hb * 0x10001u;  // packed {h,h}
            }
        }
    }
    // b2-extension row: h == 1.0 for every edge (k = 32)
    if (t < E_BLK) Hs2[t * HS_STRIDE + 32] = 0x3C003C00u;

    // ---- xh fragments (f16, reused across all K): lane's 8 f-values (f = 8g+b) per M-tile
    f32x4 acc[2][2];
    #pragma unroll
    for (int a = 0; a < 2; ++a)
        #pragma unroll
        for (int b = 0; b < 2; ++b) acc[a][b] = (f32x4){0.f, 0.f, 0.f, 0.f};

    UH8 xf[2];
    int myrow[2];
    #pragma unroll
    for (int mt = 0; mt < 2; ++mt) {
        int row = (2 * wv + mt) * 16 + j16;
        myrow[mt] = row;
        int e = e0 + row; if (e >= N_EDGES) e = N_EDGES - 1;
        int src = ei[e];
        uint4 raw = *(const uint4*)(xh + (size_t)src * F_IN + 8 * g);
        xf[mt].q[0] = raw.x; xf[mt].q[1] = raw.y; xf[mt].q[2] = raw.z; xf[mt].q[3] = raw.w;
    }

    // ---- b2-extension K-step: A = x fragment directly (h == 1)
    {
        UH8 bx0, bx1;
        *(uint4*)bx0.q = *(const uint4*)(W2T + (size_t)j16 * KW + 1024 + 8 * g);
        *(uint4*)bx1.q = *(const uint4*)(W2T + (size_t)(16 + j16) * KW + 1024 + 8 * g);
        #pragma unroll
        for (int mt = 0; mt < 2; ++mt) {
            acc[mt][0] = __builtin_amdgcn_mfma_f32_16x16x32_f16(xf[mt].h8, bx0.h8, acc[mt][0], 0, 0, 0);
            acc[mt][1] = __builtin_amdgcn_mfma_f32_16x16x32_f16(xf[mt].h8, bx1.h8, acc[mt][1], 0, 0, 0);
        }
    }

    __syncthreads();  // Hs2 (incl. cross-wave b2 row) visible to all

    // ---- K loop: 4 quarters of 256 kk, W2T staged per quarter (XOR-swizzled)
    for (int q = 0; q < 4; ++q) {
        if (q) __syncthreads();
        #pragma unroll
        for (int c = 0; c < 4; ++c) {
            int ch = c * 256 + t;
            int lbyte = ch * 16;
            int jrow = lbyte >> 9;
            int off = lbyte & 511;
            uint4 val = *(const uint4*)((const char*)W2T + (size_t)jrow * (KW * 2) + q * 512 + off);
            *(uint4*)((char*)W2q + jrow * 512 + (off ^ ((jrow & 7) << 4))) = val;
        }
        __syncthreads();

        // batched h2 fetch: 8 packed {h,h} per M-tile for k = q*8 .. q*8+7
        uint hb[2][8];
        #pragma unroll
        for (int mt = 0; mt < 2; ++mt) {
            const uint* hp = Hs2 + myrow[mt] * HS_STRIDE + q * 8;
            uint4 a = *(const uint4*)hp;
            uint4 b = *(const uint4*)(hp + 4);
            hb[mt][0] = a.x; hb[mt][1] = a.y; hb[mt][2] = a.z; hb[mt][3] = a.w;
            hb[mt][4] = b.x; hb[mt][5] = b.y; hb[mt][6] = b.z; hb[mt][7] = b.w;
        }

        #pragma unroll
        for (int kst = 0; kst < 8; ++kst) {
            int kb = kst * 64 + g * 16;
            UH8 bf0, bf1;
            *(uint4*)bf0.q = *(const uint4*)((const char*)W2q + j16 * 512 + (kb ^ ((j16 & 7) << 4)));
            *(uint4*)bf1.q = *(const uint4*)((const char*)W2q + (16 + j16) * 512 + (kb ^ ((j16 & 7) << 4)));
            #pragma unroll
            for (int mt = 0; mt < 2; ++mt) {
                UH2 h2; h2.q = hb[mt][kst];
                UH8 af;
                #pragma unroll
                for (int p = 0; p < 4; ++p) af.h2[p] = h2.h2 * xf[mt].h2[p];  // v_pk_mul_f16
                acc[mt][0] = __builtin_amdgcn_mfma_f32_16x16x32_f16(af.h8, bf0.h8, acc[mt][0], 0, 0, 0);
                acc[mt][1] = __builtin_amdgcn_mfma_f32_16x16x32_f16(af.h8, bf1.h8, acc[mt][1], 0, 0, 0);
            }
        }
    }

    // ---- scatter-add to agg[dst]
    #pragma unroll
    for (int mt = 0; mt < 2; ++mt) {
        int rowb = (2 * wv + mt) * 16 + 4 * g;
        #pragma unroll
        for (int v = 0; v < 4; ++v) {
            int e = e0 + rowb + v;
            if (e < N_EDGES) {
                int dst = ei[N_EDGES + e];
                atomicAdd(&agg[(size_t)dst * LATENT + j16],      acc[mt][0][v]);
                atomicAdd(&agg[(size_t)dst * LATENT + 16 + j16], acc[mt][1][v]);
            }
        }
    }
}

// ---------------- node update + global mean pool ----------------
// Lane l owns column l; each 32-lane group walks VN consecutive nodes with a running
// per-graph partial sum (batch sorted -> ~1 atomic flush per graph-run per stripe).
#define VN 8
__global__ __launch_bounds__(256) void nodepool_kernel(
    const float* __restrict__ x, const float* __restrict__ agg,
    const float* __restrict__ root, const float* __restrict__ cbias,
    const int* __restrict__ batch, float* __restrict__ pool,
    float* __restrict__ pcnt)
{
    int t = threadIdx.x;
    int l = t & 31;
    int stripe = t >> 5;  // 0..7
    int v0 = (blockIdx.x * 8 + stripe) * VN;
    float rc[F_IN];
    #pragma unroll
    for (int f = 0; f < F_IN; ++f) rc[f] = root[f * LATENT + l];
    float cbl = cbias[l];

    float sum = 0.f, cnt = 0.f;
    int gcur = -1;
    for (int i = 0; i < VN; ++i) {
        int v = v0 + i;
        if (v >= N_NODES) break;
        int g = batch[v];
        if (g != gcur) {
            if (gcur >= 0) {
                atomicAdd(&pool[gcur * LATENT + l], sum);
                if (l == 0) atomicAdd(&pcnt[gcur], cnt);
            }
            gcur = g; sum = 0.f; cnt = 0.f;
        }
        float xv = x[(size_t)v * F_IN + l];     // coalesced
        float a = agg[(size_t)v * LATENT + l] + cbl;
        #pragma unroll
        for (int f = 0; f < F_IN; ++f) {
            float xfv = __shfl(xv, (t & 32) | f);
            a += xfv * rc[f];
        }
        sum += fmaxf(a, 0.f);
        cnt += 1.f;
    }
    if (gcur >= 0) {
        atomicAdd(&pool[gcur * LATENT + l], sum);
        if (l == 0) atomicAdd(&pcnt[gcur], cnt);
    }
}

// ---------------- final FC ----------------
__global__ void final_kernel(const float* __restrict__ pool, const float* __restrict__ pcnt,
                             const float* __restrict__ fcw, const float* __restrict__ fcb,
                             float* __restrict__ out)
{
    int t = blockIdx.x * blockDim.x + threadIdx.x;
    int gr = t >> 7, j = t & 127;
    if (gr >= N_GRAPHS) return;
    float inv = 1.0f / fmaxf(pcnt[gr], 1.0f);
    float o = fcb[j];
    #pragma unroll 8
    for (int l = 0; l < LATENT; ++l) {
        float pv = fmaxf(pool[gr * LATENT + l] * inv, 0.0f);
        o += pv * fcw[l * EMBED + j];
    }
    out[gr * EMBED + j] = o;
}

extern "C" void kernel_launch(void* const* d_in, const int* in_sizes, int n_in,
                              void* d_out, int out_size, void* d_ws, size_t ws_size,
                              hipStream_t stream)
{
    const float* x     = (const float*)d_in[0];
    const int*   ei    = (const int*)d_in[1];
    const float* ea    = (const float*)d_in[2];
    const int*   batch = (const int*)d_in[3];
    const float* W1    = (const float*)d_in[4];
    const float* b1    = (const float*)d_in[5];
    const float* W2    = (const float*)d_in[6];
    const float* b2    = (const float*)d_in[7];
    const float* root  = (const float*)d_in[8];
    const float* cb    = (const float*)d_in[9];
    const float* fcw   = (const float*)d_in[10];
    const float* fcb   = (const float*)d_in[11];
    float* out = (float*)d_out;

    char* w = (char*)d_ws;
    auto alloc = [&](size_t bytes) {
        char* p = w;
        w += (bytes + 255) & ~size_t(255);
        return p;
    };
    ushort* W2T  = (ushort*)alloc((size_t)32 * KW * 2);
    ushort* xh   = (ushort*)alloc((size_t)N_NODES * F_IN * 2);
    float*  agg  = (float*)alloc((size_t)N_NODES * LATENT * 4);
    float*  pool = (float*)alloc(N_GRAPHS * LATENT * 4);
    float*  pcnt = (float*)alloc(N_GRAPHS * 4);

    prep_kernel<<<1563, 256, 0, stream>>>(x, W2, b2, xh, W2T, (float4*)agg, pool, pcnt);
    edge_mfma_kernel<<<N_EBLK, 256, 0, stream>>>(xh, ei, ea, W1, b1, W2T, agg);
    nodepool_kernel<<<(N_NODES + 8 * VN - 1) / (8 * VN), 256, 0, stream>>>(
        x, agg, root, cb, batch, pool, pcnt);
    final_kernel<<<(N_GRAPHS * EMBED + 255) / 256, 256, 0, stream>>>(pool, pcnt, fcw, fcb, out);
}